// Round 2
// baseline (1350.462 us; speedup 1.0000x reference)
//
#include <hip/hip_runtime.h>
#include <stdint.h>

typedef __attribute__((ext_vector_type(8))) short short8;
typedef __attribute__((ext_vector_type(4))) float floatx4;

#define INV_SQRT2F 0.70710678118654752440f

__device__ __forceinline__ float bf2f(ushort u) {
    union { uint32_t u; float f; } c; c.u = ((uint32_t)u) << 16; return c.f;
}
__device__ __forceinline__ ushort f2bf(float f) {
    union { float f; uint32_t u; } c; c.f = f;
    uint32_t x = c.u;
    return (ushort)((x + 0x7fffu + ((x >> 16) & 1u)) >> 16);  // RTNE
}
__device__ __forceinline__ float softplus100(float x) {
    float z = 100.f * x;
    return (fmaxf(z, 0.f) + log1pf(__expf(-fabsf(z)))) * 0.01f;
}
// XOR-swizzled column offset (8-elem granules): 2-way max bank aliasing (free)
__device__ __forceinline__ int swz(int row, int col) {
    return (((col >> 3) ^ (row & 7)) << 3) | (col & 7);
}

struct P9 { const void* W[9]; const float* b[9]; };
struct P4 { const void* W[4]; const float* b[4]; };
struct P3 { const void* W[3]; const float* b[3]; };
struct Cvt { const float* s[16]; ushort* d[16]; int n[16]; };

// fp32 -> bf16 weight conversion into workspace (one segment per blockIdx.y)
__global__ void k_cvt(Cvt c) {
    const int seg = blockIdx.y;
    const int n = c.n[seg];
    const float* s = c.s[seg];
    ushort* d = c.d[seg];
    for (int i = blockIdx.x * blockDim.x + threadIdx.x; i < n; i += gridDim.x * blockDim.x)
        d[i] = f2bf(s[i]);
}

// Fill act[128][STRIDE] cols 0..63 with NeRF embedding (zeros beyond 38), bf16.
template<int STRIDE>
__device__ void embed128(short* act, const float* pts, int row0, short* inp_sv) {
    for (int idx = threadIdx.x; idx < 128 * 64; idx += 512) {
        int row = idx >> 6, col = idx & 63;
        float v = 0.f;
        if (col < 39) {
            int comp = (col < 3) ? col : (col - 3) % 3;
            float x = pts[(row0 + row) * 3 + comp];
            if (col < 3) v = x;
            else {
                int b = col - 3; int fi = b / 6; int r = b % 6;
                float a = x * (float)(1 << fi);
                v = (r < 3) ? sinf(a) : cosf(a);
            }
        }
        act[row * STRIDE + swz(row, col)] = (short)f2bf(v);
        if (inp_sv && col < 39) inp_sv[row * 40 + col] = (short)f2bf(v * INV_SQRT2F);
    }
}

// One linear layer over the block's 128 rows held in LDS (bf16), fp32 accumulate.
// ACT: 0=none 1=softplus100 2=relu 3=tanh. WF32: weights are fp32 (inline cvt).
template<int ACT, int STRIDE, bool WF32>
__device__ void layer_mm(short* act, const void* Wv, const float* bias,
                         int K, int Kw, int Nout, float scale,
                         bool toLds, float* gOut, int gCol0, int gRow0)
{
    const int tid = threadIdx.x;
    const int wave = tid >> 6, lane = tid & 63;
    const int q = lane >> 4, li = lane & 15;
    const int Ttot = (Nout + 15) >> 4;

    floatx4 acc[4][8];
#pragma unroll
    for (int i = 0; i < 4; ++i)
#pragma unroll
        for (int m = 0; m < 8; ++m) acc[i][m] = (floatx4){0.f, 0.f, 0.f, 0.f};

    bool tv[4], full[4]; int nn[4];
#pragma unroll
    for (int i = 0; i < 4; ++i) {
        int t = wave + 8 * i;
        tv[i] = t < Ttot;
        full[i] = (t * 16 + 16) <= Nout;
        nn[i] = t * 16 + li;
    }

    for (int k0 = 0; k0 < K; k0 += 32) {
        short8 bfr[4];
#pragma unroll
        for (int i = 0; i < 4; ++i) {
            short8 z = {0, 0, 0, 0, 0, 0, 0, 0};
            bfr[i] = z;
            if (tv[i]) {
                int n = nn[i];
                if (full[i] && Kw == K) {
                    if (!WF32) {
                        bfr[i] = *(const short8*)((const ushort*)Wv + n * K + k0 + q * 8);
                    } else {
                        const float4* p = (const float4*)((const float*)Wv + n * K + k0 + q * 8);
                        float4 f0 = p[0], f1 = p[1];
                        bfr[i][0] = (short)f2bf(f0.x); bfr[i][1] = (short)f2bf(f0.y);
                        bfr[i][2] = (short)f2bf(f0.z); bfr[i][3] = (short)f2bf(f0.w);
                        bfr[i][4] = (short)f2bf(f1.x); bfr[i][5] = (short)f2bf(f1.y);
                        bfr[i][6] = (short)f2bf(f1.z); bfr[i][7] = (short)f2bf(f1.w);
                    }
                } else {
#pragma unroll
                    for (int j = 0; j < 8; ++j) {
                        int k = k0 + q * 8 + j;
                        short v = 0;
                        if (n < Nout && k < Kw) {
                            if (!WF32) v = (short)((const ushort*)Wv)[n * Kw + k];
                            else v = (short)f2bf(((const float*)Wv)[n * Kw + k]);
                        }
                        bfr[i][j] = v;
                    }
                }
            }
        }
        short8 afr[8];
        const int gq = (k0 >> 3) + q;
#pragma unroll
        for (int m = 0; m < 8; ++m) {
            int row = m * 16 + li;
            afr[m] = *(const short8*)&act[row * STRIDE + ((gq ^ (row & 7)) << 3)];
        }
#pragma unroll
        for (int i = 0; i < 4; ++i) {
            if (!tv[i]) continue;
#pragma unroll
            for (int m = 0; m < 8; ++m)
                acc[i][m] = __builtin_amdgcn_mfma_f32_16x16x32_bf16(afr[m], bfr[i], acc[i][m], 0, 0, 0);
        }
    }
    __syncthreads();  // all reads of act done before epilogue overwrites
#pragma unroll
    for (int i = 0; i < 4; ++i) {
        if (!tv[i]) continue;
        int n = nn[i];
        if (n < Nout) {
            float bs = bias[n];
#pragma unroll
            for (int m = 0; m < 8; ++m) {
                int rbase = m * 16 + q * 4;
#pragma unroll
                for (int r = 0; r < 4; ++r) {
                    float v = acc[i][m][r] + bs;
                    if (ACT == 1) v = softplus100(v);
                    else if (ACT == 2) v = fmaxf(v, 0.f);
                    else if (ACT == 3) v = tanhf(v);
                    v *= scale;
                    if (toLds) act[(rbase + r) * STRIDE + swz(rbase + r, n)] = (short)f2bf(v);
                    else gOut[(size_t)(gRow0 + rbase + r) * 263 + gCol0 + n] = v;
                }
            }
        }
    }
}

template<bool WF32>
__global__ __launch_bounds__(512, 2) void k_implicit(const float* __restrict__ pts,
                                                     P9 p, float* __restrict__ out) {
    __shared__ short act[128 * 512];
    __shared__ short inp_sv[128 * 40];
    const int row0 = blockIdx.x * 128;
    embed128<512>(act, pts, row0, inp_sv);
    __syncthreads();
    layer_mm<1, 512, WF32>(act, p.W[0], p.b[0], 64, 39, 512, 1.f, true, nullptr, 0, 0);
    __syncthreads();
    layer_mm<1, 512, WF32>(act, p.W[1], p.b[1], 512, 512, 512, 1.f, true, nullptr, 0, 0);
    __syncthreads();
    layer_mm<1, 512, WF32>(act, p.W[2], p.b[2], 512, 512, 512, 1.f, true, nullptr, 0, 0);
    __syncthreads();
    // layer 3: softplus, then pre-scale by 1/sqrt(2) (skip-concat scale)
    layer_mm<1, 512, WF32>(act, p.W[3], p.b[3], 512, 512, 473, INV_SQRT2F, true, nullptr, 0, 0);
    // append inp * 1/sqrt(2) into cols 473..511 (disjoint from epilogue writes)
    for (int idx = threadIdx.x; idx < 128 * 64; idx += 512) {
        int row = idx >> 6, col = idx & 63;
        if (col < 39) act[row * 512 + swz(row, 473 + col)] = inp_sv[row * 40 + col];
    }
    __syncthreads();
    layer_mm<1, 512, WF32>(act, p.W[4], p.b[4], 512, 512, 512, 1.f, true, nullptr, 0, 0);
    __syncthreads();
    layer_mm<1, 512, WF32>(act, p.W[5], p.b[5], 512, 512, 512, 1.f, true, nullptr, 0, 0);
    __syncthreads();
    layer_mm<1, 512, WF32>(act, p.W[6], p.b[6], 512, 512, 512, 1.f, true, nullptr, 0, 0);
    __syncthreads();
    layer_mm<1, 512, WF32>(act, p.W[7], p.b[7], 512, 512, 512, 1.f, true, nullptr, 0, 0);
    __syncthreads();
    layer_mm<0, 512, WF32>(act, p.W[8], p.b[8], 512, 512, 257, 1.f, false, out, 0, row0);
}

template<bool WF32>
__global__ __launch_bounds__(512, 2) void k_disp(const float* __restrict__ pts,
                                                 P4 p, float* __restrict__ out) {
    __shared__ short act[128 * 512];
    const int row0 = blockIdx.x * 128;
    embed128<512>(act, pts, row0, nullptr);
    __syncthreads();
    layer_mm<2, 512, WF32>(act, p.W[0], p.b[0], 64, 39, 512, 1.f, true, nullptr, 0, 0);
    __syncthreads();
    layer_mm<2, 512, WF32>(act, p.W[1], p.b[1], 512, 512, 512, 1.f, true, nullptr, 0, 0);
    __syncthreads();
    layer_mm<2, 512, WF32>(act, p.W[2], p.b[2], 512, 512, 512, 1.f, true, nullptr, 0, 0);
    __syncthreads();
    layer_mm<3, 512, WF32>(act, p.W[3], p.b[3], 512, 512, 3, 1.f, false, out, 257, row0);
}

template<bool WF32>
__global__ __launch_bounds__(512, 2) void k_mult(const float* __restrict__ pts,
                                                 P3 p, float* __restrict__ out, int rows_per_cluster) {
    __shared__ short act[128 * 128];
    const int row0 = blockIdx.x * 128;
    const int c = row0 / rows_per_cluster;
    const void* w0; const void* w1; const void* w2;
    if (WF32) {
        w0 = (const void*)((const float*)p.W[0] + c * 128 * 39);
        w1 = (const void*)((const float*)p.W[1] + c * 128 * 128);
        w2 = (const void*)((const float*)p.W[2] + c * 3 * 128);
    } else {
        w0 = (const void*)((const ushort*)p.W[0] + c * 128 * 39);
        w1 = (const void*)((const ushort*)p.W[1] + c * 128 * 128);
        w2 = (const void*)((const ushort*)p.W[2] + c * 3 * 128);
    }
    embed128<128>(act, pts, row0, nullptr);
    __syncthreads();
    layer_mm<2, 128, WF32>(act, w0, p.b[0] + c * 128, 64, 39, 128, 1.f, true, nullptr, 0, 0);
    __syncthreads();
    layer_mm<2, 128, WF32>(act, w1, p.b[1] + c * 128, 128, 128, 128, 1.f, true, nullptr, 0, 0);
    __syncthreads();
    layer_mm<3, 128, WF32>(act, w2, p.b[2] + c * 3, 128, 128, 3, 1.f, false, out, 260, row0);
}

extern "C" void kernel_launch(void* const* d_in, const int* in_sizes, int n_in,
                              void* d_out, int out_size, void* d_ws, size_t ws_size,
                              hipStream_t stream) {
    const float* pts = (const float*)d_in[0];
    float* out = (float*)d_out;
    const int N = in_sizes[0] / 3;       // 32768
    const int nb = N / 128;              // 256 blocks
    const int rpc = N / 64;              // rows per cluster (512)

    // weight element counts, in d_in order
    const int isz[9] = {512 * 39, 512 * 512, 512 * 512, 473 * 512, 512 * 512,
                        512 * 512, 512 * 512, 512 * 512, 257 * 512};
    const int dsz[4] = {512 * 39, 512 * 512, 512 * 512, 3 * 512};
    const int msz[3] = {64 * 128 * 39, 64 * 128 * 128, 64 * 3 * 128};

    size_t total = 0;
    for (int l = 0; l < 9; ++l) total += isz[l];
    for (int l = 0; l < 4; ++l) total += dsz[l];
    for (int l = 0; l < 3; ++l) total += msz[l];
    const bool use_ws = ws_size >= total * sizeof(ushort);

    P9 ip; P4 dp; P3 mp;
    for (int l = 0; l < 9; ++l) { ip.W[l] = d_in[1 + 2 * l];  ip.b[l] = (const float*)d_in[2 + 2 * l]; }
    for (int l = 0; l < 4; ++l) { dp.W[l] = d_in[19 + 2 * l]; dp.b[l] = (const float*)d_in[20 + 2 * l]; }
    for (int l = 0; l < 3; ++l) { mp.W[l] = d_in[27 + 2 * l]; mp.b[l] = (const float*)d_in[28 + 2 * l]; }

    if (use_ws) {
        ushort* wsp = (ushort*)d_ws;
        Cvt cv;
        size_t off = 0; int seg = 0;
        for (int l = 0; l < 9; ++l) {
            cv.s[seg] = (const float*)ip.W[l]; cv.d[seg] = wsp + off; cv.n[seg] = isz[l];
            ip.W[l] = (const void*)(wsp + off); off += isz[l]; ++seg;
        }
        for (int l = 0; l < 4; ++l) {
            cv.s[seg] = (const float*)dp.W[l]; cv.d[seg] = wsp + off; cv.n[seg] = dsz[l];
            dp.W[l] = (const void*)(wsp + off); off += dsz[l]; ++seg;
        }
        for (int l = 0; l < 3; ++l) {
            cv.s[seg] = (const float*)mp.W[l]; cv.d[seg] = wsp + off; cv.n[seg] = msz[l];
            mp.W[l] = (const void*)(wsp + off); off += msz[l]; ++seg;
        }
        k_cvt<<<dim3(256, 16), 256, 0, stream>>>(cv);
        k_implicit<false><<<nb, 512, 0, stream>>>(pts, ip, out);
        k_disp<false><<<nb, 512, 0, stream>>>(pts, dp, out);
        k_mult<false><<<nb, 512, 0, stream>>>(pts, mp, out, rpc);
    } else {
        k_implicit<true><<<nb, 512, 0, stream>>>(pts, ip, out);
        k_disp<true><<<nb, 512, 0, stream>>>(pts, dp, out);
        k_mult<true><<<nb, 512, 0, stream>>>(pts, mp, out, rpc);
    }
}

// Round 3
// 648.901 us; speedup vs baseline: 2.0812x; 2.0812x over previous
//
#include <hip/hip_runtime.h>
#include <stdint.h>

typedef __attribute__((ext_vector_type(8))) short short8;
typedef __attribute__((ext_vector_type(4))) float floatx4;

#define INV_SQRT2F 0.70710678118654752440f

__device__ __forceinline__ ushort f2bf(float f) {
    union { float f; uint32_t u; } c; c.f = f;
    uint32_t x = c.u;
    return (ushort)((x + 0x7fffu + ((x >> 16) & 1u)) >> 16);  // RTNE
}
// softplus(beta=100): (max(z,0) + log(1+exp(-|z|)))/100 with native exp/log.
// The log term is <= ln2 and its ~1e-7 abs error vanishes under bf16 rounding.
__device__ __forceinline__ float softplus100(float x) {
    float z = 100.f * x;
    return (fmaxf(z, 0.f) + __logf(1.f + __expf(-fabsf(z)))) * 0.01f;
}
// XOR-swizzled column offset (8-elem granules): 2-way max bank aliasing (free)
__device__ __forceinline__ int swz(int row, int col) {
    return (((col >> 3) ^ (row & 7)) << 3) | (col & 7);
}

struct P9 { const void* W[9]; const float* b[9]; };
struct P4 { const void* W[4]; const float* b[4]; };
struct P3 { const void* W[3]; const float* b[3]; };
struct Cvt { const float* s[16]; ushort* d[16]; int n[16]; };

// fp32 -> bf16 weight conversion into workspace (one segment per blockIdx.y)
__global__ void k_cvt(Cvt c) {
    const int seg = blockIdx.y;
    const int n = c.n[seg];
    const float* s = c.s[seg];
    ushort* d = c.d[seg];
    for (int i = blockIdx.x * blockDim.x + threadIdx.x; i < n; i += gridDim.x * blockDim.x)
        d[i] = f2bf(s[i]);
}

// Fill act[64][STRIDE] cols 0..63 with NeRF embedding (zeros beyond 38), bf16.
template<int STRIDE>
__device__ void embed64(short* act, const float* pts, int row0, short* inp_sv) {
    for (int idx = threadIdx.x; idx < 64 * 64; idx += 512) {
        int row = idx >> 6, col = idx & 63;
        float v = 0.f;
        if (col < 39) {
            int comp = (col < 3) ? col : (col - 3) % 3;
            float x = pts[(row0 + row) * 3 + comp];
            if (col < 3) v = x;
            else {
                int b = col - 3; int fi = b / 6; int r = b % 6;
                float a = x * (float)(1 << fi);
                v = (r < 3) ? __sinf(a) : __cosf(a);
            }
        }
        act[row * STRIDE + swz(row, col)] = (short)f2bf(v);
        if (inp_sv && col < 39) inp_sv[row * 40 + col] = (short)f2bf(v * INV_SQRT2F);
    }
}

// One linear layer over the block's 64 rows held in LDS (bf16), fp32 accumulate.
// ACT: 0=none 1=softplus100 2=relu 3=tanh. WF32: weights are fp32 (inline cvt).
template<int ACT, int STRIDE, bool WF32>
__device__ void layer_mm(short* act, const void* Wv, const float* bias,
                         int K, int Kw, int Nout, float scale,
                         bool toLds, float* gOut, int gCol0, int gRow0)
{
    const int tid = threadIdx.x;
    const int wave = tid >> 6, lane = tid & 63;
    const int q = lane >> 4, li = lane & 15;
    const int Ttot = (Nout + 15) >> 4;

    floatx4 acc[4][4];
#pragma unroll
    for (int i = 0; i < 4; ++i)
#pragma unroll
        for (int m = 0; m < 4; ++m) acc[i][m] = (floatx4){0.f, 0.f, 0.f, 0.f};

    bool tv[4], full[4]; int nn[4];
#pragma unroll
    for (int i = 0; i < 4; ++i) {
        int t = wave + 8 * i;
        tv[i] = t < Ttot;
        full[i] = (t * 16 + 16) <= Nout;
        nn[i] = t * 16 + li;
    }

    auto loadB = [&](int k0, short8* bfr) {
#pragma unroll
        for (int i = 0; i < 4; ++i) {
            short8 z = {0, 0, 0, 0, 0, 0, 0, 0};
            bfr[i] = z;
            if (tv[i]) {
                int n = nn[i];
                if (full[i] && Kw == K) {
                    if (!WF32) {
                        bfr[i] = *(const short8*)((const ushort*)Wv + n * K + k0 + q * 8);
                    } else {
                        const float4* p = (const float4*)((const float*)Wv + n * K + k0 + q * 8);
                        float4 f0 = p[0], f1 = p[1];
                        bfr[i][0] = (short)f2bf(f0.x); bfr[i][1] = (short)f2bf(f0.y);
                        bfr[i][2] = (short)f2bf(f0.z); bfr[i][3] = (short)f2bf(f0.w);
                        bfr[i][4] = (short)f2bf(f1.x); bfr[i][5] = (short)f2bf(f1.y);
                        bfr[i][6] = (short)f2bf(f1.z); bfr[i][7] = (short)f2bf(f1.w);
                    }
                } else {
#pragma unroll
                    for (int j = 0; j < 8; ++j) {
                        int k = k0 + q * 8 + j;
                        short v = 0;
                        if (n < Nout && k < Kw) {
                            if (!WF32) v = (short)((const ushort*)Wv)[n * Kw + k];
                            else v = (short)f2bf(((const float*)Wv)[n * Kw + k]);
                        }
                        bfr[i][j] = v;
                    }
                }
            }
        }
    };

    short8 bcur[4];
    loadB(0, bcur);
    for (int k0 = 0; k0 < K; k0 += 32) {
        short8 bnxt[4];
        const bool more = (k0 + 32) < K;
        if (more) loadB(k0 + 32, bnxt);
        short8 afr[4];
        const int gq = (k0 >> 3) + q;
#pragma unroll
        for (int m = 0; m < 4; ++m) {
            int row = m * 16 + li;
            afr[m] = *(const short8*)&act[row * STRIDE + ((gq ^ (row & 7)) << 3)];
        }
#pragma unroll
        for (int i = 0; i < 4; ++i) {
            if (!tv[i]) continue;
#pragma unroll
            for (int m = 0; m < 4; ++m)
                acc[i][m] = __builtin_amdgcn_mfma_f32_16x16x32_bf16(afr[m], bcur[i], acc[i][m], 0, 0, 0);
        }
        if (more) {
#pragma unroll
            for (int i = 0; i < 4; ++i) bcur[i] = bnxt[i];
        }
    }
    __syncthreads();  // all reads of act done before epilogue overwrites
#pragma unroll
    for (int i = 0; i < 4; ++i) {
        if (!tv[i]) continue;
        int n = nn[i];
        if (n < Nout) {
            float bs = bias[n];
#pragma unroll
            for (int m = 0; m < 4; ++m) {
                int rbase = m * 16 + q * 4;
#pragma unroll
                for (int r = 0; r < 4; ++r) {
                    float v = acc[i][m][r] + bs;
                    if (ACT == 1) v = softplus100(v);
                    else if (ACT == 2) v = fmaxf(v, 0.f);
                    else if (ACT == 3) v = tanhf(v);
                    v *= scale;
                    if (toLds) act[(rbase + r) * STRIDE + swz(rbase + r, n)] = (short)f2bf(v);
                    else gOut[(size_t)(gRow0 + rbase + r) * 263 + gCol0 + n] = v;
                }
            }
        }
    }
}

template<bool WF32>
__global__ __launch_bounds__(512, 4) void k_implicit(const float* __restrict__ pts,
                                                     P9 p, float* __restrict__ out) {
    __shared__ short act[64 * 512];
    __shared__ short inp_sv[64 * 40];
    const int row0 = blockIdx.x * 64;
    embed64<512>(act, pts, row0, inp_sv);
    __syncthreads();
    layer_mm<1, 512, WF32>(act, p.W[0], p.b[0], 64, 39, 512, 1.f, true, nullptr, 0, 0);
    __syncthreads();
    layer_mm<1, 512, WF32>(act, p.W[1], p.b[1], 512, 512, 512, 1.f, true, nullptr, 0, 0);
    __syncthreads();
    layer_mm<1, 512, WF32>(act, p.W[2], p.b[2], 512, 512, 512, 1.f, true, nullptr, 0, 0);
    __syncthreads();
    // layer 3: softplus, then pre-scale by 1/sqrt(2) (skip-concat scale)
    layer_mm<1, 512, WF32>(act, p.W[3], p.b[3], 512, 512, 473, INV_SQRT2F, true, nullptr, 0, 0);
    // append inp * 1/sqrt(2) into cols 473..511 (disjoint from epilogue writes)
    for (int idx = threadIdx.x; idx < 64 * 64; idx += 512) {
        int row = idx >> 6, col = idx & 63;
        if (col < 39) act[row * 512 + swz(row, 473 + col)] = inp_sv[row * 40 + col];
    }
    __syncthreads();
    layer_mm<1, 512, WF32>(act, p.W[4], p.b[4], 512, 512, 512, 1.f, true, nullptr, 0, 0);
    __syncthreads();
    layer_mm<1, 512, WF32>(act, p.W[5], p.b[5], 512, 512, 512, 1.f, true, nullptr, 0, 0);
    __syncthreads();
    layer_mm<1, 512, WF32>(act, p.W[6], p.b[6], 512, 512, 512, 1.f, true, nullptr, 0, 0);
    __syncthreads();
    layer_mm<1, 512, WF32>(act, p.W[7], p.b[7], 512, 512, 512, 1.f, true, nullptr, 0, 0);
    __syncthreads();
    layer_mm<0, 512, WF32>(act, p.W[8], p.b[8], 512, 512, 257, 1.f, false, out, 0, row0);
}

template<bool WF32>
__global__ __launch_bounds__(512, 4) void k_disp(const float* __restrict__ pts,
                                                 P4 p, float* __restrict__ out) {
    __shared__ short act[64 * 512];
    const int row0 = blockIdx.x * 64;
    embed64<512>(act, pts, row0, nullptr);
    __syncthreads();
    layer_mm<2, 512, WF32>(act, p.W[0], p.b[0], 64, 39, 512, 1.f, true, nullptr, 0, 0);
    __syncthreads();
    layer_mm<2, 512, WF32>(act, p.W[1], p.b[1], 512, 512, 512, 1.f, true, nullptr, 0, 0);
    __syncthreads();
    layer_mm<2, 512, WF32>(act, p.W[2], p.b[2], 512, 512, 512, 1.f, true, nullptr, 0, 0);
    __syncthreads();
    layer_mm<3, 512, WF32>(act, p.W[3], p.b[3], 512, 512, 3, 1.f, false, out, 257, row0);
}

template<bool WF32>
__global__ __launch_bounds__(512, 4) void k_mult(const float* __restrict__ pts,
                                                 P3 p, float* __restrict__ out, int rows_per_cluster) {
    __shared__ short act[64 * 128];
    const int row0 = blockIdx.x * 64;
    const int c = row0 / rows_per_cluster;
    const void* w0; const void* w1; const void* w2;
    if (WF32) {
        w0 = (const void*)((const float*)p.W[0] + c * 128 * 39);
        w1 = (const void*)((const float*)p.W[1] + c * 128 * 128);
        w2 = (const void*)((const float*)p.W[2] + c * 3 * 128);
    } else {
        w0 = (const void*)((const ushort*)p.W[0] + c * 128 * 39);
        w1 = (const void*)((const ushort*)p.W[1] + c * 128 * 128);
        w2 = (const void*)((const ushort*)p.W[2] + c * 3 * 128);
    }
    embed64<128>(act, pts, row0, nullptr);
    __syncthreads();
    layer_mm<2, 128, WF32>(act, w0, p.b[0] + c * 128, 64, 39, 128, 1.f, true, nullptr, 0, 0);
    __syncthreads();
    layer_mm<2, 128, WF32>(act, w1, p.b[1] + c * 128, 128, 128, 128, 1.f, true, nullptr, 0, 0);
    __syncthreads();
    layer_mm<3, 128, WF32>(act, w2, p.b[2] + c * 3, 128, 128, 3, 1.f, false, out, 260, row0);
}

extern "C" void kernel_launch(void* const* d_in, const int* in_sizes, int n_in,
                              void* d_out, int out_size, void* d_ws, size_t ws_size,
                              hipStream_t stream) {
    const float* pts = (const float*)d_in[0];
    float* out = (float*)d_out;
    const int N = in_sizes[0] / 3;       // 32768
    const int nb = N / 64;               // 512 blocks (64 rows each)
    const int rpc = N / 64;              // rows per cluster (512)

    // weight element counts, in d_in order
    const int isz[9] = {512 * 39, 512 * 512, 512 * 512, 473 * 512, 512 * 512,
                        512 * 512, 512 * 512, 512 * 512, 257 * 512};
    const int dsz[4] = {512 * 39, 512 * 512, 512 * 512, 3 * 512};
    const int msz[3] = {64 * 128 * 39, 64 * 128 * 128, 64 * 3 * 128};

    size_t total = 0;
    for (int l = 0; l < 9; ++l) total += isz[l];
    for (int l = 0; l < 4; ++l) total += dsz[l];
    for (int l = 0; l < 3; ++l) total += msz[l];
    const bool use_ws = ws_size >= total * sizeof(ushort);

    P9 ip; P4 dp; P3 mp;
    for (int l = 0; l < 9; ++l) { ip.W[l] = d_in[1 + 2 * l];  ip.b[l] = (const float*)d_in[2 + 2 * l]; }
    for (int l = 0; l < 4; ++l) { dp.W[l] = d_in[19 + 2 * l]; dp.b[l] = (const float*)d_in[20 + 2 * l]; }
    for (int l = 0; l < 3; ++l) { mp.W[l] = d_in[27 + 2 * l]; mp.b[l] = (const float*)d_in[28 + 2 * l]; }

    if (use_ws) {
        ushort* wsp = (ushort*)d_ws;
        Cvt cv;
        size_t off = 0; int seg = 0;
        for (int l = 0; l < 9; ++l) {
            cv.s[seg] = (const float*)ip.W[l]; cv.d[seg] = wsp + off; cv.n[seg] = isz[l];
            ip.W[l] = (const void*)(wsp + off); off += isz[l]; ++seg;
        }
        for (int l = 0; l < 4; ++l) {
            cv.s[seg] = (const float*)dp.W[l]; cv.d[seg] = wsp + off; cv.n[seg] = dsz[l];
            dp.W[l] = (const void*)(wsp + off); off += dsz[l]; ++seg;
        }
        for (int l = 0; l < 3; ++l) {
            cv.s[seg] = (const float*)mp.W[l]; cv.d[seg] = wsp + off; cv.n[seg] = msz[l];
            mp.W[l] = (const void*)(wsp + off); off += msz[l]; ++seg;
        }
        k_cvt<<<dim3(256, 16), 256, 0, stream>>>(cv);
        k_implicit<false><<<nb, 512, 0, stream>>>(pts, ip, out);
        k_disp<false><<<nb, 512, 0, stream>>>(pts, dp, out);
        k_mult<false><<<nb, 512, 0, stream>>>(pts, mp, out, rpc);
    } else {
        k_implicit<true><<<nb, 512, 0, stream>>>(pts, ip, out);
        k_disp<true><<<nb, 512, 0, stream>>>(pts, dp, out);
        k_mult<true><<<nb, 512, 0, stream>>>(pts, mp, out, rpc);
    }
}